// Round 4
// baseline (5084.116 us; speedup 1.0000x reference)
//
#include <hip/hip_runtime.h>
#include <cstdint>
#include <cstddef>

#define DEV __device__ __forceinline__

typedef __attribute__((ext_vector_type(8))) short    short8;   // 8 bf16
typedef __attribute__((ext_vector_type(4))) float    f32x4;
typedef __attribute__((ext_vector_type(8))) _Float16 f16x8;

static constexpr int B_ = 128, T_ = 1024, F_ = 128, H_ = 128, L_ = 7;
static constexpr int G4 = 512;           // 4*H
static constexpr int M_ = B_ * T_;       // 131072

// ---------- numeric helpers ----------
DEV float b2f(unsigned short u){ union{unsigned int i; float f;} v; v.i = ((unsigned)u)<<16; return v.f; }
DEV float b2f_lo(unsigned int u){ union{unsigned int i; float f;} v; v.i = u<<16; return v.f; }
DEV float b2f_hi(unsigned int u){ union{unsigned int i; float f;} v; v.i = u & 0xffff0000u; return v.f; }
DEV unsigned short f2b(float f){
  union{float f; unsigned int i;} v; v.f = f;
  unsigned int r = v.i + 0x7FFF + ((v.i >> 16) & 1);
  return (unsigned short)(r >> 16);
}
DEV float fexp2(float x){
#if __has_builtin(__builtin_amdgcn_exp2f)
  return __builtin_amdgcn_exp2f(x);
#else
  return exp2f(x);
#endif
}
DEV float frcp(float x){
#if __has_builtin(__builtin_amdgcn_rcpf)
  return __builtin_amdgcn_rcpf(x);
#else
  return 1.0f/x;
#endif
}
DEV float fsig(float x){ return frcp(1.f + fexp2(-1.44269504f*x)); }
DEV float ftanh(float x){
  x = fminf(10.f, fmaxf(-10.f, x));
  float e = fexp2(2.88539008f*x);
  return (e - 1.f) * frcp(e + 1.f);
}

// ---------- converts ----------
__global__ void k_cvt_x(const float4* __restrict__ x4, ushort4* __restrict__ xb4, int n4){
  int i = blockIdx.x*blockDim.x + threadIdx.x;
  int stride = gridDim.x*blockDim.x;
  for (; i < n4; i += stride){
    float4 v = x4[i];
    ushort4 o; o.x = f2b(v.x); o.y = f2b(v.y); o.z = f2b(v.z); o.w = f2b(v.w);
    xb4[i] = o;
  }
}

// Wih rows are PERMUTED at convert time: dest row j (within a layer) takes
// source gate-row (j&3)*128 + (j>>2). k_gemm then writes xg with columns in
// [h_row*4 + gate] order with UNCHANGED, fully-coalesced code, and k_recur
// reads the 4 gates of one h-row as a single dwordx4/x2.
__global__ void k_cvt_w(const float* __restrict__ Wih, const float* __restrict__ Whh,
                        const float* __restrict__ bih, const float* __restrict__ bhh,
                        unsigned short* __restrict__ wihb, _Float16* __restrict__ whhh,
                        float* __restrict__ bias){
  int i = blockIdx.x*blockDim.x + threadIdx.x;
  const int nw = L_*G4*F_;                       // 458752
  int stride = gridDim.x*blockDim.x;
  for (int k = i; k < nw; k += stride){
    int layer = k >> 16;            // 512*128 per layer
    int rem   = k & 65535;
    int row   = rem >> 7;
    int col   = rem & 127;
    int srow  = ((row & 3) << 7) | (row >> 2);
    wihb[k] = f2b(Wih[((size_t)layer << 16) | (srow << 7) | col]);
    whhh[k] = (_Float16)Whh[k];     // Whh stays gate-major (k_recur indexes it directly)
  }
  if (i < L_*G4){
    int layer = i >> 9;
    int row   = i & 511;
    int srow  = ((row & 3) << 7) | (row >> 2);
    int s = (layer << 9) | srow;
    bias[i] = bih[s] + bhh[s];
  }
}

// ---------- GEMM: xg[M,512] = in[M,128] * Wih^T + bias (cols pre-permuted) ----------
template<bool XGF32>
__global__ __launch_bounds__(256) void k_gemm(const unsigned short* __restrict__ A,
                                              const unsigned short* __restrict__ W,
                                              const float* __restrict__ bias,
                                              void* __restrict__ xgv){
  int bid = blockIdx.x;
  int xcd = bid & 7;
  int j   = bid >> 3;
  int mt  = xcd*128 + (j >> 3);   // [0,1024) 128-row tiles; XCD-local streaming
  int nt  = j & 7;                // [0,8) 64-col tiles
  int wv  = threadIdx.x >> 6;
  int lane = threadIdx.x & 63;
  int lr = lane & 15, lk = lane >> 4;
  int m0 = mt*128 + wv*32;
  int n0 = nt*64;
  const unsigned short* a0p = A + (size_t)(m0 + lr)*F_ + lk*8;
  const unsigned short* b0p = W + (size_t)(n0 + lr)*F_ + lk*8;
  f32x4 acc[2][4] = {};
#pragma unroll
  for (int kt = 0; kt < 4; ++kt){
    short8 a0 = *(const short8*)(a0p + kt*32);
    short8 a1 = *(const short8*)(a0p + 16*F_ + kt*32);
    short8 w0 = *(const short8*)(b0p + kt*32);
    short8 w1 = *(const short8*)(b0p + 16*F_ + kt*32);
    short8 w2 = *(const short8*)(b0p + 32*F_ + kt*32);
    short8 w3 = *(const short8*)(b0p + 48*F_ + kt*32);
    acc[0][0] = __builtin_amdgcn_mfma_f32_16x16x32_bf16(a0, w0, acc[0][0], 0, 0, 0);
    acc[0][1] = __builtin_amdgcn_mfma_f32_16x16x32_bf16(a0, w1, acc[0][1], 0, 0, 0);
    acc[0][2] = __builtin_amdgcn_mfma_f32_16x16x32_bf16(a0, w2, acc[0][2], 0, 0, 0);
    acc[0][3] = __builtin_amdgcn_mfma_f32_16x16x32_bf16(a0, w3, acc[0][3], 0, 0, 0);
    acc[1][0] = __builtin_amdgcn_mfma_f32_16x16x32_bf16(a1, w0, acc[1][0], 0, 0, 0);
    acc[1][1] = __builtin_amdgcn_mfma_f32_16x16x32_bf16(a1, w1, acc[1][1], 0, 0, 0);
    acc[1][2] = __builtin_amdgcn_mfma_f32_16x16x32_bf16(a1, w2, acc[1][2], 0, 0, 0);
    acc[1][3] = __builtin_amdgcn_mfma_f32_16x16x32_bf16(a1, w3, acc[1][3], 0, 0, 0);
  }
  float bcol[4];
#pragma unroll
  for (int nf = 0; nf < 4; ++nf) bcol[nf] = bias[n0 + nf*16 + lr];
#pragma unroll
  for (int mf = 0; mf < 2; ++mf)
#pragma unroll
    for (int nf = 0; nf < 4; ++nf)
#pragma unroll
      for (int r = 0; r < 4; ++r){
        int row = m0 + mf*16 + lk*4 + r;
        int col = n0 + nf*16 + lr;
        float v = acc[mf][nf][r] + bcol[nf];
        if constexpr (XGF32) ((float*)xgv)[(size_t)row*G4 + col] = v;
        else ((unsigned short*)xgv)[(size_t)row*G4 + col] = f2b(v);
      }
}

// ---------- recurrence: MFMA-broadcast, VALU-thin ----------
// One WG (8 waves) per batch element; wave w owns h-rows [16w,16w+16).
// z = Whh·h via mfma_f32_16x16x32_f16, B = h broadcast to 16 columns.
// A-row m = 4*rowoff+gate -> lane (q,i) reg r of tile tau = gate r of
// h-row 16w+4*tau+q. Lane consumes tile tau* = i&3 (row myrow = 16w+4*(i&3)+q).
// x-gates enter as the MFMA C-operand of each tau chain (wrong-x in discarded
// tiles is harmless) -> no zero-init movs, no z adds. One dwordx4 x-load/step.
// One lgkmcnt-only barrier per step; x loads/h stores stay in flight.
template<bool XGF32>
__global__ __launch_bounds__(512) void k_recur(const void* __restrict__ xgv,
                                               const _Float16* __restrict__ Wh,
                                               unsigned short* __restrict__ hout){
  const int b = blockIdx.x;
  const int tid = threadIdx.x;
  const int w = tid >> 6, l = tid & 63;
  const int q = l >> 4, i = l & 15;
  const int gsel = i & 3;
  const int rbit = i >> 2;
  const int myrow = 16*w + 4*gsel + q;

  __shared__ __align__(16) _Float16 hsh[2][H_];

  f16x8 wf[4][4];
  {
    const _Float16* base = Wh + ((size_t)gsel*H_ + 16*w + rbit)*H_ + 8*q;
#pragma unroll
    for (int tau = 0; tau < 4; ++tau)
#pragma unroll
      for (int kk = 0; kk < 4; ++kk)
        wf[tau][kk] = *(const f16x8*)(base + (size_t)(4*tau)*H_ + kk*32);
  }

  if (tid < H_) hsh[0][tid] = (_Float16)0.f;
  float c = 0.f;

  const float4*  xf = (const float4*) xgv + (size_t)b*T_*128 + myrow;
  const ushort4* xb = (const ushort4*)xgv + (size_t)b*T_*128 + myrow;
  auto ldx = [&](int t) -> f32x4 {
    if constexpr (XGF32){ float4 v = xf[(size_t)t*128]; f32x4 r = {v.x, v.y, v.z, v.w}; return r; }
    else { ushort4 u = xb[(size_t)t*128]; f32x4 r = {b2f(u.x), b2f(u.y), b2f(u.z), b2f(u.w)}; return r; }
  };
  f32x4 x0 = ldx(0), x1 = ldx(1);

  const bool c0 = (gsel & 1) != 0, c1 = (gsel & 2) != 0;
  __syncthreads();

  int buf = 0;
  for (int t = 0; t < T_; ++t){
    const _Float16* hp = hsh[buf];
    f16x8 h0 = *(const f16x8*)(hp +  0 + 8*q);
    f16x8 h1 = *(const f16x8*)(hp + 32 + 8*q);
    f16x8 h2 = *(const f16x8*)(hp + 64 + 8*q);
    f16x8 h3 = *(const f16x8*)(hp + 96 + 8*q);
    f32x4 a0 = __builtin_amdgcn_mfma_f32_16x16x32_f16(wf[0][0], h0, x0, 0, 0, 0);
    f32x4 a1 = __builtin_amdgcn_mfma_f32_16x16x32_f16(wf[1][0], h0, x0, 0, 0, 0);
    f32x4 a2 = __builtin_amdgcn_mfma_f32_16x16x32_f16(wf[2][0], h0, x0, 0, 0, 0);
    f32x4 a3 = __builtin_amdgcn_mfma_f32_16x16x32_f16(wf[3][0], h0, x0, 0, 0, 0);
    a0 = __builtin_amdgcn_mfma_f32_16x16x32_f16(wf[0][1], h1, a0, 0, 0, 0);
    a1 = __builtin_amdgcn_mfma_f32_16x16x32_f16(wf[1][1], h1, a1, 0, 0, 0);
    a2 = __builtin_amdgcn_mfma_f32_16x16x32_f16(wf[2][1], h1, a2, 0, 0, 0);
    a3 = __builtin_amdgcn_mfma_f32_16x16x32_f16(wf[3][1], h1, a3, 0, 0, 0);
    a0 = __builtin_amdgcn_mfma_f32_16x16x32_f16(wf[0][2], h2, a0, 0, 0, 0);
    a1 = __builtin_amdgcn_mfma_f32_16x16x32_f16(wf[1][2], h2, a1, 0, 0, 0);
    a2 = __builtin_amdgcn_mfma_f32_16x16x32_f16(wf[2][2], h2, a2, 0, 0, 0);
    a3 = __builtin_amdgcn_mfma_f32_16x16x32_f16(wf[3][2], h2, a3, 0, 0, 0);
    a0 = __builtin_amdgcn_mfma_f32_16x16x32_f16(wf[0][3], h3, a0, 0, 0, 0);
    a1 = __builtin_amdgcn_mfma_f32_16x16x32_f16(wf[1][3], h3, a1, 0, 0, 0);
    a2 = __builtin_amdgcn_mfma_f32_16x16x32_f16(wf[2][3], h3, a2, 0, 0, 0);
    a3 = __builtin_amdgcn_mfma_f32_16x16x32_f16(wf[3][3], h3, a3, 0, 0, 0);
    // select tile tau* = gsel
    f32x4 t0 = c0 ? a1 : a0;
    f32x4 t1 = c0 ? a3 : a2;
    f32x4 z  = c1 ? t1 : t0;
    // rotate 2-deep prefetch (stays in flight across the barrier)
    int tc = (t + 2 < T_) ? t + 2 : T_ - 1;
    x0 = x1; x1 = ldx(tc);

    c = fsig(z[1])*c + fsig(z[0])*ftanh(z[2]);
    float h = fsig(z[3])*ftanh(c);
    if (i < 4){                       // rows 16w..16w+15 written by 16 lanes/wave
      hsh[buf ^ 1][myrow] = (_Float16)h;
      hout[(size_t)(b*T_ + t)*H_ + myrow] = f2b(h);
    }
    asm volatile("s_waitcnt lgkmcnt(0)\n\ts_barrier" ::: "memory");
    buf ^= 1;
  }
}

// ---------- attention (only head A-1 matters) + final linear + sigmoid ----------
__global__ __launch_bounds__(256) void k_attn(const unsigned short* __restrict__ out,
                                              const float* __restrict__ Wa, const float* __restrict__ ba,
                                              const float* __restrict__ Wf, const float* __restrict__ bfv,
                                              float* __restrict__ y){
  int b = blockIdx.x, tid = threadIdx.x;
  __shared__ float was[H_];
  __shared__ float p[T_];
  __shared__ float red[64];
  __shared__ float app[256];
  if (tid < H_) was[tid] = Wa[127*H_ + tid];
  __syncthreads();
  float bav = ba[127];
  for (int t = tid; t < T_; t += 256){
    const unsigned short* row = out + (size_t)(b*T_ + t)*H_;
    float acc = 0.f;
#pragma unroll
    for (int k = 0; k < H_; k += 8){
      uint4 u = *(const uint4*)(row + k);
      acc += b2f_lo(u.x)*was[k+0] + b2f_hi(u.x)*was[k+1];
      acc += b2f_lo(u.y)*was[k+2] + b2f_hi(u.y)*was[k+3];
      acc += b2f_lo(u.z)*was[k+4] + b2f_hi(u.z)*was[k+5];
      acc += b2f_lo(u.w)*was[k+6] + b2f_hi(u.w)*was[k+7];
    }
    p[t] = ftanh(acc + bav);
  }
  __syncthreads();
  float m = -1e30f;
  for (int t = tid; t < T_; t += 256) m = fmaxf(m, p[t]);
  for (int off = 32; off; off >>= 1) m = fmaxf(m, __shfl_xor(m, off));
  if ((tid & 63) == 0) red[tid >> 6] = m;
  __syncthreads();
  if (tid == 0) red[8] = fmaxf(fmaxf(red[0], red[1]), fmaxf(red[2], red[3]));
  __syncthreads();
  float smax = red[8];
  float lsum = 0.f;
  for (int t = tid; t < T_; t += 256){
    float e = fexp2(1.44269504f*(p[t] - smax));
    p[t] = e; lsum += e;
  }
  for (int off = 32; off; off >>= 1) lsum += __shfl_xor(lsum, off);
  if ((tid & 63) == 0) red[16 + (tid >> 6)] = lsum;
  __syncthreads();
  float rden = frcp(red[16] + red[17] + red[18] + red[19]);
  int h = tid & (H_ - 1);
  int half = tid >> 7;
  float acc = 0.f;
  for (int t = half*512; t < half*512 + 512; ++t)
    acc += p[t] * b2f(out[(size_t)(b*T_ + t)*H_ + h]);
  app[tid] = acc;
  __syncthreads();
  if (tid < H_){
    float applied = (app[tid] + app[tid + H_]) * rden;
    float v = applied * Wf[tid];
    for (int off = 32; off; off >>= 1) v += __shfl_xor(v, off);
    if (tid == 0)  red[32] = v;
    if (tid == 64) red[33] = v;
  }
  __syncthreads();
  if (tid == 0) y[b] = fsig(red[32] + red[33] + bfv[0]);
}

// ---------- launch ----------
extern "C" void kernel_launch(void* const* d_in, const int* in_sizes, int n_in,
                              void* d_out, int out_size, void* d_ws, size_t ws_size,
                              hipStream_t stream){
  const float* x   = (const float*)d_in[0];
  const float* Wih = (const float*)d_in[1];
  const float* Whh = (const float*)d_in[2];
  const float* bih = (const float*)d_in[3];
  const float* bhh = (const float*)d_in[4];
  const float* Wa  = (const float*)d_in[5];
  const float* ba  = (const float*)d_in[6];
  const float* Wf  = (const float*)d_in[7];
  const float* bfv = (const float*)d_in[8];
  float* y = (float*)d_out;

  char* ws = (char*)d_ws;
  size_t off = 0;
  auto alloc = [&](size_t bytes) -> void* {
    void* p = ws + off; off += (bytes + 255) & ~(size_t)255; return p;
  };
  unsigned short* wihb = (unsigned short*)alloc((size_t)L_*G4*F_*2);
  _Float16*       whhh = (_Float16*)      alloc((size_t)L_*G4*F_*2);
  float*          bias = (float*)         alloc((size_t)L_*G4*4);
  unsigned short* bufA = (unsigned short*)alloc((size_t)M_*H_*2);
  unsigned short* bufB = (unsigned short*)alloc((size_t)M_*H_*2);
  size_t xg_f32_bytes = (size_t)M_*G4*4;
  bool xgf32 = (off + xg_f32_bytes) <= ws_size;
  void* xg = alloc(xgf32 ? xg_f32_bytes : xg_f32_bytes/2);

  k_cvt_x<<<2048, 256, 0, stream>>>((const float4*)x, (ushort4*)bufA, M_*F_/4);
  k_cvt_w<<<1792, 256, 0, stream>>>(Wih, Whh, bih, bhh, wihb, whhh, bias);

  const unsigned short* cur = bufA;
  unsigned short* nxt = bufB;
  for (int l = 0; l < L_; ++l){
    const unsigned short* wl  = wihb + (size_t)l*G4*F_;
    const _Float16*       whl = whhh + (size_t)l*G4*F_;
    const float*          bl  = bias + l*G4;
    if (xgf32){
      k_gemm<true ><<<8192, 256, 0, stream>>>(cur, wl, bl, xg);
      k_recur<true ><<<128, 512, 0, stream>>>(xg, whl, nxt);
    } else {
      k_gemm<false><<<8192, 256, 0, stream>>>(cur, wl, bl, xg);
      k_recur<false><<<128, 512, 0, stream>>>(xg, whl, nxt);
    }
    const unsigned short* tmp = cur; cur = nxt; nxt = (unsigned short*)const_cast<unsigned short*>(tmp);
  }
  k_attn<<<128, 256, 0, stream>>>(cur, Wa, ba, Wf, bfv, y);
}

// Round 5
// 4629.923 us; speedup vs baseline: 1.0981x; 1.0981x over previous
//
#include <hip/hip_runtime.h>
#include <cstdint>
#include <cstddef>

#define DEV __device__ __forceinline__

typedef __attribute__((ext_vector_type(8))) short    short8;   // 8 bf16
typedef __attribute__((ext_vector_type(4))) float    f32x4;
typedef __attribute__((ext_vector_type(2))) _Float16 f16x2;
typedef __attribute__((ext_vector_type(8))) _Float16 f16x8;

static constexpr int B_ = 128, T_ = 1024, F_ = 128, H_ = 128, L_ = 7;
static constexpr int G4 = 512;           // 4*H
static constexpr int M_ = B_ * T_;       // 131072

// ---------- numeric helpers ----------
DEV float b2f(unsigned short u){ union{unsigned int i; float f;} v; v.i = ((unsigned)u)<<16; return v.f; }
DEV float b2f_lo(unsigned int u){ union{unsigned int i; float f;} v; v.i = u<<16; return v.f; }
DEV float b2f_hi(unsigned int u){ union{unsigned int i; float f;} v; v.i = u & 0xffff0000u; return v.f; }
DEV unsigned short f2b(float f){
  union{float f; unsigned int i;} v; v.f = f;
  unsigned int r = v.i + 0x7FFF + ((v.i >> 16) & 1);
  return (unsigned short)(r >> 16);
}
DEV float fexp2(float x){
#if __has_builtin(__builtin_amdgcn_exp2f)
  return __builtin_amdgcn_exp2f(x);
#else
  return exp2f(x);
#endif
}
DEV float frcp(float x){
#if __has_builtin(__builtin_amdgcn_rcpf)
  return __builtin_amdgcn_rcpf(x);
#else
  return 1.0f/x;
#endif
}
DEV float fsig(float x){ return frcp(1.f + fexp2(-1.44269504f*x)); }
DEV float ftanh(float x){
  x = fminf(10.f, fmaxf(-10.f, x));
  float e = fexp2(2.88539008f*x);
  return (e - 1.f) * frcp(e + 1.f);
}

// ---------- converts ----------
__global__ void k_cvt_x(const float4* __restrict__ x4, ushort4* __restrict__ xb4, int n4){
  int i = blockIdx.x*blockDim.x + threadIdx.x;
  int stride = gridDim.x*blockDim.x;
  for (; i < n4; i += stride){
    float4 v = x4[i];
    ushort4 o; o.x = f2b(v.x); o.y = f2b(v.y); o.z = f2b(v.z); o.w = f2b(v.w);
    xb4[i] = o;
  }
}

// Wih rows are PERMUTED at convert time: dest row j (within a layer) takes
// source gate-row (j&3)*128 + (j>>2). k_gemm then writes xg with columns in
// [h_row*4 + gate] order with UNCHANGED, fully-coalesced code, and k_recur
// reads the 4 gates of one h-row as a single dwordx2.
__global__ void k_cvt_w(const float* __restrict__ Wih, const float* __restrict__ Whh,
                        const float* __restrict__ bih, const float* __restrict__ bhh,
                        unsigned short* __restrict__ wihb, _Float16* __restrict__ whhh,
                        float* __restrict__ bias){
  int i = blockIdx.x*blockDim.x + threadIdx.x;
  const int nw = L_*G4*F_;                       // 458752
  int stride = gridDim.x*blockDim.x;
  for (int k = i; k < nw; k += stride){
    int layer = k >> 16;            // 512*128 per layer
    int rem   = k & 65535;
    int row   = rem >> 7;
    int col   = rem & 127;
    int srow  = ((row & 3) << 7) | (row >> 2);
    wihb[k] = f2b(Wih[((size_t)layer << 16) | (srow << 7) | col]);
    whhh[k] = (_Float16)Whh[k];     // Whh stays gate-major (k_recur indexes it directly)
  }
  if (i < L_*G4){
    int layer = i >> 9;
    int row   = i & 511;
    int srow  = ((row & 3) << 7) | (row >> 2);
    int s = (layer << 9) | srow;
    bias[i] = bih[s] + bhh[s];
  }
}

// ---------- GEMM: xg[M,512] = in[M,128] * Wih^T + bias (cols pre-permuted) ----------
__global__ __launch_bounds__(256) void k_gemm(const unsigned short* __restrict__ A,
                                              const unsigned short* __restrict__ W,
                                              const float* __restrict__ bias,
                                              unsigned short* __restrict__ xg){
  int bid = blockIdx.x;
  int xcd = bid & 7;
  int j   = bid >> 3;
  int mt  = xcd*128 + (j >> 3);   // [0,1024) 128-row tiles; XCD-local streaming
  int nt  = j & 7;                // [0,8) 64-col tiles
  int wv  = threadIdx.x >> 6;
  int lane = threadIdx.x & 63;
  int lr = lane & 15, lk = lane >> 4;
  int m0 = mt*128 + wv*32;
  int n0 = nt*64;
  const unsigned short* a0p = A + (size_t)(m0 + lr)*F_ + lk*8;
  const unsigned short* b0p = W + (size_t)(n0 + lr)*F_ + lk*8;
  f32x4 acc[2][4] = {};
#pragma unroll
  for (int kt = 0; kt < 4; ++kt){
    short8 a0 = *(const short8*)(a0p + kt*32);
    short8 a1 = *(const short8*)(a0p + 16*F_ + kt*32);
    short8 w0 = *(const short8*)(b0p + kt*32);
    short8 w1 = *(const short8*)(b0p + 16*F_ + kt*32);
    short8 w2 = *(const short8*)(b0p + 32*F_ + kt*32);
    short8 w3 = *(const short8*)(b0p + 48*F_ + kt*32);
    acc[0][0] = __builtin_amdgcn_mfma_f32_16x16x32_bf16(a0, w0, acc[0][0], 0, 0, 0);
    acc[0][1] = __builtin_amdgcn_mfma_f32_16x16x32_bf16(a0, w1, acc[0][1], 0, 0, 0);
    acc[0][2] = __builtin_amdgcn_mfma_f32_16x16x32_bf16(a0, w2, acc[0][2], 0, 0, 0);
    acc[0][3] = __builtin_amdgcn_mfma_f32_16x16x32_bf16(a0, w3, acc[0][3], 0, 0, 0);
    acc[1][0] = __builtin_amdgcn_mfma_f32_16x16x32_bf16(a1, w0, acc[1][0], 0, 0, 0);
    acc[1][1] = __builtin_amdgcn_mfma_f32_16x16x32_bf16(a1, w1, acc[1][1], 0, 0, 0);
    acc[1][2] = __builtin_amdgcn_mfma_f32_16x16x32_bf16(a1, w2, acc[1][2], 0, 0, 0);
    acc[1][3] = __builtin_amdgcn_mfma_f32_16x16x32_bf16(a1, w3, acc[1][3], 0, 0, 0);
  }
  float bcol[4];
#pragma unroll
  for (int nf = 0; nf < 4; ++nf) bcol[nf] = bias[n0 + nf*16 + lr];
#pragma unroll
  for (int mf = 0; mf < 2; ++mf)
#pragma unroll
    for (int nf = 0; nf < 4; ++nf)
#pragma unroll
      for (int r = 0; r < 4; ++r){
        int row = m0 + mf*16 + lk*4 + r;
        int col = n0 + nf*16 + lr;
        xg[(size_t)row*G4 + col] = f2b(acc[mf][nf][r] + bcol[nf]);
      }
}

// ---------- recurrence: MFMA-broadcast, ZERO per-step VMEM ----------
// One WG (8 waves) per batch element; wave w owns h-rows [16w,16w+16).
// z = Whh·h via mfma_f32_16x16x32_f16, B = h broadcast to 16 columns;
// A-row m = 4*rowoff+gate -> lane (q,i) tile tau=i&3 holds gates i,f,g,o of
// h-row 16w+4*(i&3)+q in its f32x4. x enters as the MFMA C operand.
// t-loop unrolled x8: x is a double-buffered REGISTER ring (8 ushort4 loads
// issued one 8-step group ahead); h history kept in an 8-deep LDS ring and
// flushed to global ONCE per group as a contiguous, coalesced 2KB block.
// Steady-state step has NO global load/store -> no vmcnt stalls; per-step
// barrier waits lgkmcnt only.
__global__ __launch_bounds__(512) void k_recur(const unsigned short* __restrict__ xg,
                                               const _Float16* __restrict__ Wh,
                                               unsigned short* __restrict__ hout){
  const int b = blockIdx.x;
  const int tid = threadIdx.x;
  const int w = tid >> 6, l = tid & 63;
  const int q = l >> 4, i = l & 15;
  const int gsel = i & 3;
  const int rbit = i >> 2;
  const int myrow = 16*w + 4*gsel + q;

  __shared__ __align__(16) _Float16 hh[8][H_];   // h ring: slot s = h_{t: t%8==s}

  f16x8 wf[4][4];
  {
    const _Float16* base = Wh + ((size_t)gsel*H_ + 16*w + rbit)*H_ + 8*q;
#pragma unroll
    for (int tau = 0; tau < 4; ++tau)
#pragma unroll
      for (int kk = 0; kk < 4; ++kk)
        wf[tau][kk] = *(const f16x8*)(base + (size_t)(4*tau)*H_ + kk*32);
  }

  if (tid < H_) hh[0][tid] = (_Float16)0.f;
  float c = 0.f;

  const ushort4* xp = (const ushort4*)xg + (size_t)b*T_*128 + myrow;
  const bool c0 = (gsel & 1) != 0, c1 = (gsel & 2) != 0;

  // current-group x regs (steps t0..t0+7) and next-group regs
  ushort4 xa0 = xp[0*128], xa1 = xp[1*128], xa2 = xp[2*128], xa3 = xp[3*128],
          xa4 = xp[4*128], xa5 = xp[5*128], xa6 = xp[6*128], xa7 = xp[7*128];
  ushort4 xb0, xb1, xb2, xb3, xb4, xb5, xb6, xb7;

  __syncthreads();

#define STEP(J, XV)                                                              \
  {                                                                              \
    const _Float16* hp = hh[J];                                                  \
    f16x8 h0 = *(const f16x8*)(hp +  0 + 8*q);                                   \
    f16x8 h1 = *(const f16x8*)(hp + 32 + 8*q);                                   \
    f16x8 h2 = *(const f16x8*)(hp + 64 + 8*q);                                   \
    f16x8 h3 = *(const f16x8*)(hp + 96 + 8*q);                                   \
    f32x4 xc = {b2f(XV.x), b2f(XV.y), b2f(XV.z), b2f(XV.w)};                     \
    f32x4 a0 = __builtin_amdgcn_mfma_f32_16x16x32_f16(wf[0][0], h0, xc, 0, 0, 0);\
    f32x4 a1 = __builtin_amdgcn_mfma_f32_16x16x32_f16(wf[1][0], h0, xc, 0, 0, 0);\
    f32x4 a2 = __builtin_amdgcn_mfma_f32_16x16x32_f16(wf[2][0], h0, xc, 0, 0, 0);\
    f32x4 a3 = __builtin_amdgcn_mfma_f32_16x16x32_f16(wf[3][0], h0, xc, 0, 0, 0);\
    a0 = __builtin_amdgcn_mfma_f32_16x16x32_f16(wf[0][1], h1, a0, 0, 0, 0);      \
    a1 = __builtin_amdgcn_mfma_f32_16x16x32_f16(wf[1][1], h1, a1, 0, 0, 0);      \
    a2 = __builtin_amdgcn_mfma_f32_16x16x32_f16(wf[2][1], h1, a2, 0, 0, 0);      \
    a3 = __builtin_amdgcn_mfma_f32_16x16x32_f16(wf[3][1], h1, a3, 0, 0, 0);      \
    a0 = __builtin_amdgcn_mfma_f32_16x16x32_f16(wf[0][2], h2, a0, 0, 0, 0);      \
    a1 = __builtin_amdgcn_mfma_f32_16x16x32_f16(wf[1][2], h2, a1, 0, 0, 0);      \
    a2 = __builtin_amdgcn_mfma_f32_16x16x32_f16(wf[2][2], h2, a2, 0, 0, 0);      \
    a3 = __builtin_amdgcn_mfma_f32_16x16x32_f16(wf[3][2], h2, a3, 0, 0, 0);      \
    a0 = __builtin_amdgcn_mfma_f32_16x16x32_f16(wf[0][3], h3, a0, 0, 0, 0);      \
    a1 = __builtin_amdgcn_mfma_f32_16x16x32_f16(wf[1][3], h3, a1, 0, 0, 0);      \
    a2 = __builtin_amdgcn_mfma_f32_16x16x32_f16(wf[2][3], h3, a2, 0, 0, 0);      \
    a3 = __builtin_amdgcn_mfma_f32_16x16x32_f16(wf[3][3], h3, a3, 0, 0, 0);      \
    f32x4 t0s = c0 ? a1 : a0;                                                    \
    f32x4 t1s = c0 ? a3 : a2;                                                    \
    f32x4 z   = c1 ? t1s : t0s;                                                  \
    c = fsig(z[1])*c + fsig(z[0])*ftanh(z[2]);                                   \
    float hval = fsig(z[3])*ftanh(c);                                            \
    if (i < 4) hh[(J + 1) & 7][myrow] = (_Float16)hval;                          \
    asm volatile("s_waitcnt lgkmcnt(0)\n\ts_barrier" ::: "memory");              \
  }

  // flush indexing: position p=2*tid -> step k=p>>7 (slot (k+1)&7), row r=p&127
  const int fk = (2*tid) >> 7;
  const int fr = (2*tid) & 127;
  const _Float16* fsrc = &hh[(fk + 1) & 7][fr];
  unsigned int* hdst = (unsigned int*)hout + (size_t)b*T_*64 + tid;

  for (int t0 = 0; t0 < T_; t0 += 8){
    int tn = t0 + 8;
    if (tn < T_){
      const ushort4* xq = xp + (size_t)tn*128;
      xb0 = xq[0*128]; xb1 = xq[1*128]; xb2 = xq[2*128]; xb3 = xq[3*128];
      xb4 = xq[4*128]; xb5 = xq[5*128]; xb6 = xq[6*128]; xb7 = xq[7*128];
    }
    STEP(0, xa0) STEP(1, xa1) STEP(2, xa2) STEP(3, xa3)
    STEP(4, xa4) STEP(5, xa5) STEP(6, xa6) STEP(7, xa7)
    // cooperative flush: 8 steps x 128 rows = contiguous 2KB, 1 dword/thread
    {
      f16x2 hv = *(const f16x2*)fsrc;
      unsigned int d = (unsigned int)f2b((float)hv[0]) |
                       ((unsigned int)f2b((float)hv[1]) << 16);
      hdst[(size_t)t0*64] = d;
      // guard: flush reads must complete before next group's step-0 write
      asm volatile("s_waitcnt lgkmcnt(0)\n\ts_barrier" ::: "memory");
    }
    xa0 = xb0; xa1 = xb1; xa2 = xb2; xa3 = xb3;
    xa4 = xb4; xa5 = xb5; xa6 = xb6; xa7 = xb7;
  }
#undef STEP
}

// ---------- attention (only head A-1 matters) + final linear + sigmoid ----------
__global__ __launch_bounds__(256) void k_attn(const unsigned short* __restrict__ out,
                                              const float* __restrict__ Wa, const float* __restrict__ ba,
                                              const float* __restrict__ Wf, const float* __restrict__ bfv,
                                              float* __restrict__ y){
  int b = blockIdx.x, tid = threadIdx.x;
  __shared__ float was[H_];
  __shared__ float p[T_];
  __shared__ float red[64];
  __shared__ float app[256];
  if (tid < H_) was[tid] = Wa[127*H_ + tid];
  __syncthreads();
  float bav = ba[127];
  for (int t = tid; t < T_; t += 256){
    const unsigned short* row = out + (size_t)(b*T_ + t)*H_;
    float acc = 0.f;
#pragma unroll
    for (int k = 0; k < H_; k += 8){
      uint4 u = *(const uint4*)(row + k);
      acc += b2f_lo(u.x)*was[k+0] + b2f_hi(u.x)*was[k+1];
      acc += b2f_lo(u.y)*was[k+2] + b2f_hi(u.y)*was[k+3];
      acc += b2f_lo(u.z)*was[k+4] + b2f_hi(u.z)*was[k+5];
      acc += b2f_lo(u.w)*was[k+6] + b2f_hi(u.w)*was[k+7];
    }
    p[t] = ftanh(acc + bav);
  }
  __syncthreads();
  float m = -1e30f;
  for (int t = tid; t < T_; t += 256) m = fmaxf(m, p[t]);
  for (int off = 32; off; off >>= 1) m = fmaxf(m, __shfl_xor(m, off));
  if ((tid & 63) == 0) red[tid >> 6] = m;
  __syncthreads();
  if (tid == 0) red[8] = fmaxf(fmaxf(red[0], red[1]), fmaxf(red[2], red[3]));
  __syncthreads();
  float smax = red[8];
  float lsum = 0.f;
  for (int t = tid; t < T_; t += 256){
    float e = fexp2(1.44269504f*(p[t] - smax));
    p[t] = e; lsum += e;
  }
  for (int off = 32; off; off >>= 1) lsum += __shfl_xor(lsum, off);
  if ((tid & 63) == 0) red[16 + (tid >> 6)] = lsum;
  __syncthreads();
  float rden = frcp(red[16] + red[17] + red[18] + red[19]);
  int h = tid & (H_ - 1);
  int half = tid >> 7;
  float acc = 0.f;
  for (int t = half*512; t < half*512 + 512; ++t)
    acc += p[t] * b2f(out[(size_t)(b*T_ + t)*H_ + h]);
  app[tid] = acc;
  __syncthreads();
  if (tid < H_){
    float applied = (app[tid] + app[tid + H_]) * rden;
    float v = applied * Wf[tid];
    for (int off = 32; off; off >>= 1) v += __shfl_xor(v, off);
    if (tid == 0)  red[32] = v;
    if (tid == 64) red[33] = v;
  }
  __syncthreads();
  if (tid == 0) y[b] = fsig(red[32] + red[33] + bfv[0]);
}

// ---------- launch ----------
extern "C" void kernel_launch(void* const* d_in, const int* in_sizes, int n_in,
                              void* d_out, int out_size, void* d_ws, size_t ws_size,
                              hipStream_t stream){
  const float* x   = (const float*)d_in[0];
  const float* Wih = (const float*)d_in[1];
  const float* Whh = (const float*)d_in[2];
  const float* bih = (const float*)d_in[3];
  const float* bhh = (const float*)d_in[4];
  const float* Wa  = (const float*)d_in[5];
  const float* ba  = (const float*)d_in[6];
  const float* Wf  = (const float*)d_in[7];
  const float* bfv = (const float*)d_in[8];
  float* y = (float*)d_out;

  char* ws = (char*)d_ws;
  size_t off = 0;
  auto alloc = [&](size_t bytes) -> void* {
    void* p = ws + off; off += (bytes + 255) & ~(size_t)255; return p;
  };
  unsigned short* wihb = (unsigned short*)alloc((size_t)L_*G4*F_*2);
  _Float16*       whhh = (_Float16*)      alloc((size_t)L_*G4*F_*2);
  float*          bias = (float*)         alloc((size_t)L_*G4*4);
  unsigned short* bufA = (unsigned short*)alloc((size_t)M_*H_*2);
  unsigned short* bufB = (unsigned short*)alloc((size_t)M_*H_*2);
  unsigned short* xg   = (unsigned short*)alloc((size_t)M_*G4*2);

  k_cvt_x<<<2048, 256, 0, stream>>>((const float4*)x, (ushort4*)bufA, M_*F_/4);
  k_cvt_w<<<1792, 256, 0, stream>>>(Wih, Whh, bih, bhh, wihb, whhh, bias);

  const unsigned short* cur = bufA;
  unsigned short* nxt = bufB;
  for (int l = 0; l < L_; ++l){
    const unsigned short* wl  = wihb + (size_t)l*G4*F_;
    const _Float16*       whl = whhh + (size_t)l*G4*F_;
    const float*          bl  = bias + l*G4;
    k_gemm <<<8192, 256, 0, stream>>>(cur, wl, bl, xg);
    k_recur<<<128, 512, 0, stream>>>(xg, whl, nxt);
    const unsigned short* tmp = cur; cur = nxt; nxt = (unsigned short*)const_cast<unsigned short*>(tmp);
  }
  k_attn<<<128, 256, 0, stream>>>(cur, Wa, ba, Wf, bfv, y);
}

// Round 6
// 1357.817 us; speedup vs baseline: 3.7443x; 3.4098x over previous
//
#include <hip/hip_runtime.h>
#include <cstdint>
#include <cstddef>

#define DEV __device__ __forceinline__

typedef __attribute__((ext_vector_type(4))) float    f32x4;
typedef __attribute__((ext_vector_type(4))) _Float16 f16x4;
typedef __attribute__((ext_vector_type(8))) _Float16 f16x8;

static constexpr int B_ = 128, T_ = 1024, F_ = 128, H_ = 128, L_ = 7;
static constexpr int M_ = B_ * T_;       // 131072

// ---------- numeric helpers ----------
DEV float fexp2(float x){
#if __has_builtin(__builtin_amdgcn_exp2f)
  return __builtin_amdgcn_exp2f(x);
#else
  return exp2f(x);
#endif
}
DEV float frcp(float x){
#if __has_builtin(__builtin_amdgcn_rcpf)
  return __builtin_amdgcn_rcpf(x);
#else
  return 1.0f/x;
#endif
}
DEV float fsig(float x){ return frcp(1.f + fexp2(-1.44269504f*x)); }
DEV float ftanh(float x){
  x = fminf(10.f, fmaxf(-10.f, x));
  float e = fexp2(2.88539008f*x);
  return (e - 1.f) * frcp(e + 1.f);
}

// ---------- converts ----------
__global__ void k_cvt_x(const float4* __restrict__ x4, f16x4* __restrict__ xo, int n4){
  int i = blockIdx.x*blockDim.x + threadIdx.x;
  int stride = gridDim.x*blockDim.x;
  for (; i < n4; i += stride){
    float4 v = x4[i];
    f16x4 o = {(_Float16)v.x, (_Float16)v.y, (_Float16)v.z, (_Float16)v.w};
    xo[i] = o;
  }
}

// Wc[l][m][k] f16, m in gate-interleaved order: gate=m&3, hrow=m>>2;
// k<128 -> Whh[l][gate*128+hrow][k], k>=128 -> Wih[l][gate*128+hrow][k-128].
// biasp[l][hrow][gate] = bih+bhh (f32).
__global__ void k_cvt_w(const float* __restrict__ Wih, const float* __restrict__ Whh,
                        const float* __restrict__ bih, const float* __restrict__ bhh,
                        _Float16* __restrict__ Wc, float* __restrict__ biasp){
  int idx = blockIdx.x*blockDim.x + threadIdx.x;          // 3584*256 = 917504 exact
  int l    = idx >> 17;            // /(512*256)
  int rem  = idx & 131071;
  int m    = rem >> 8;
  int k    = rem & 255;
  int gate = m & 3, hrow = m >> 2;
  int srow = l*512 + gate*128 + hrow;
  float v = (k < 128) ? Whh[(size_t)srow*128 + k] : Wih[(size_t)srow*128 + (k-128)];
  Wc[idx] = (_Float16)v;
  if (idx < L_*512){
    int bl = idx >> 9, r = idx & 511;
    int bh = r >> 2, bg = r & 3;
    int s = bl*512 + bg*128 + bh;
    biasp[idx] = bih[s] + bhh[s];
  }
}

// ---------- fused wavefront recurrence ----------
// Grid = 56 WGs: wg = layer*8 + group. Each WG: 512 thr (8 waves), 16 batches.
// Per step: z[512 gate-rows x 16 batches] = Wc(512x256) * [h;x](256x16) + bias,
// via 32 mfma_f32_16x16x32_f16 per wave (4 m-tiles x 8 k-tiles), A=weights in
// VGPRs (128 regs), B = hx LDS tile [16 batches][260] f16 (h | x halves).
// Lane (q=l>>4, i=l&15): m-tile mt holds all 4 gates of h-row 16w+4mt+q for
// batch i in one f32x4 -> in-lane gate math (4 h per lane).
// Cross-layer wavefront: layer l reads rows from layer l-1's output buffer,
// gated by per-8-step flags (release/acquire, agent scope). Buffers rotate by
// layer parity; flag-chain lag makes overwrites safe.
__global__ __launch_bounds__(512, 2) void k_recur(
    const _Float16* __restrict__ xcvt,
    _Float16* __restrict__ buf0, _Float16* __restrict__ buf1,
    const _Float16* __restrict__ Wc, const float4* __restrict__ biasp,
    int* __restrict__ flags){
  const int wg = blockIdx.x;
  const int layer = wg >> 3;
  const int g = wg & 7;
  const int tid = threadIdx.x;
  const int w = tid >> 6, l64 = tid & 63;
  const int q = l64 >> 4, i = l64 & 15;

  const _Float16* src = (layer == 0) ? xcvt : (((layer - 1) & 1) ? buf1 : buf0);
  _Float16* dst = (layer & 1) ? buf1 : buf0;

  __shared__ _Float16 hx[2][16][260];   // [h(128) | x(128) | pad]

  // A-frags: wf[mt][kt], row m = 16*(4w+mt)+i, k = 32kt+8q..+8
  f16x8 wf[4][8];
  {
    const _Float16* wbase = Wc + ((size_t)layer*512 + i)*256 + 8*q;
#pragma unroll
    for (int mt = 0; mt < 4; ++mt)
#pragma unroll
      for (int kt = 0; kt < 8; ++kt)
        wf[mt][kt] = *(const f16x8*)(wbase + (size_t)(16*(4*w+mt))*256 + 32*kt);
  }
  f32x4 bs[4];
#pragma unroll
  for (int mt = 0; mt < 4; ++mt){
    float4 bv = biasp[layer*128 + 4*(4*w+mt) + q];
    f32x4 t = {bv.x, bv.y, bv.z, bv.w};
    bs[mt] = t;
  }
  float cst[4] = {0.f, 0.f, 0.f, 0.f};

  // staging/flush roles
  const int bb = tid >> 5;          // batch 0..15
  const int cc = tid & 31;          // 4-elem chunk 0..31
  const size_t srow = ((size_t)(g*16 + bb))*T_*H_;
  const _Float16* xsrc = src + srow + cc*4;
  _Float16*       hdst = dst + srow + cc*4;
  int* fIn  = flags + ((layer - 1)*8 + g)*128;
  int* fOut = flags + (layer*8 + g)*128;

  auto poll = [&](int* p){
    if (tid == 0){
      while (__hip_atomic_load(p, __ATOMIC_ACQUIRE, __HIP_MEMORY_SCOPE_AGENT) == 0)
        __builtin_amdgcn_s_sleep(2);
    }
    __syncthreads();
  };

  // prologue: zero h-part, stage x row 0
  if (layer > 0) poll(fIn + 0);
  {
    f16x4 z4 = {(_Float16)0.f, (_Float16)0.f, (_Float16)0.f, (_Float16)0.f};
    *(f16x4*)&hx[0][bb][cc*4] = z4;                 // h part zero
    f16x4 x0 = *(const f16x4*)(xsrc);               // row 0
    *(f16x4*)&hx[0][bb][128 + cc*4] = x0;
  }
  __syncthreads();

  for (int t = 0; t < T_; ++t){
    const int cur = t & 1, nxt = cur ^ 1;
    if (layer > 0 && ((t + 1) & 7) == 0 && (t + 1) < T_) poll(fIn + ((t + 1) >> 3));
    // x prefetch for t+1 (clamped; row 1023 re-read harmlessly at t=1023)
    int tp = (t + 1 < T_) ? t + 1 : T_ - 1;
    f16x4 xreg = *(const f16x4*)(xsrc + (size_t)tp*H_);
    // flush row t-1 (h state entering this step) from hx[cur]
    f16x4 freg;
    if (t > 0) freg = *(const f16x4*)&hx[cur][bb][cc*4];
    // B-frags: 8 x ds_read_b128
    f16x8 bf[8];
#pragma unroll
    for (int kt = 0; kt < 8; ++kt)
      bf[kt] = *(const f16x8*)&hx[cur][i][32*kt + 8*q];
    // MFMA: 4 m-tiles x 8 k-tiles, C init = bias
    f32x4 acc[4];
#pragma unroll
    for (int mt = 0; mt < 4; ++mt){
      acc[mt] = bs[mt];
#pragma unroll
      for (int kt = 0; kt < 8; ++kt)
        acc[mt] = __builtin_amdgcn_mfma_f32_16x16x32_f16(wf[mt][kt], bf[kt], acc[mt], 0, 0, 0);
    }
    if (t > 0) *(f16x4*)(hdst + (size_t)(t - 1)*H_) = freg;   // global store (fire & forget)
    // gates: 4 h-rows per lane (batch i, hrow 16w+4mt+q)
#pragma unroll
    for (int mt = 0; mt < 4; ++mt){
      f32x4 z = acc[mt];
      cst[mt] = fsig(z[1])*cst[mt] + fsig(z[0])*ftanh(z[2]);
      float h = fsig(z[3])*ftanh(cst[mt]);
      hx[nxt][i][4*(4*w + mt) + q] = (_Float16)h;
    }
    // x(t+1) into next buffer (compiler waits vmcnt for xreg)
    *(f16x4*)&hx[nxt][bb][128 + cc*4] = xreg;
    asm volatile("s_waitcnt lgkmcnt(0)\n\ts_barrier" ::: "memory");
    // group boundary: rows <= t-1 flushed; publish group t/8-1
    if (layer < 6 && t > 0 && (t & 7) == 0){
      asm volatile("s_waitcnt vmcnt(0)" ::: "memory");
      __syncthreads();
      if (tid == 0)
        __hip_atomic_store(fOut + ((t >> 3) - 1), 1, __ATOMIC_RELEASE, __HIP_MEMORY_SCOPE_AGENT);
    }
  }
  // final flush: row 1023 lives in hx[T_&1 = 0]
  {
    f16x4 freg = *(const f16x4*)&hx[0][bb][cc*4];
    *(f16x4*)(hdst + (size_t)(T_ - 1)*H_) = freg;
  }
  if (layer < 6){
    asm volatile("s_waitcnt vmcnt(0)" ::: "memory");
    __syncthreads();
    if (tid == 0)
      __hip_atomic_store(fOut + 127, 1, __ATOMIC_RELEASE, __HIP_MEMORY_SCOPE_AGENT);
  }
}

// ---------- attention (only head A-1 matters) + final linear + sigmoid ----------
__global__ __launch_bounds__(256) void k_attn(const _Float16* __restrict__ out,
                                              const float* __restrict__ Wa, const float* __restrict__ ba,
                                              const float* __restrict__ Wf, const float* __restrict__ bfv,
                                              float* __restrict__ y){
  int b = blockIdx.x, tid = threadIdx.x;
  __shared__ float was[H_];
  __shared__ float p[T_];
  __shared__ float red[64];
  __shared__ float app[256];
  if (tid < H_) was[tid] = Wa[127*H_ + tid];
  __syncthreads();
  float bav = ba[127];
  for (int t = tid; t < T_; t += 256){
    const _Float16* row = out + (size_t)(b*T_ + t)*H_;
    float acc = 0.f;
#pragma unroll
    for (int k = 0; k < H_; k += 8){
      f16x8 u = *(const f16x8*)(row + k);
      acc += (float)u[0]*was[k+0] + (float)u[1]*was[k+1]
           + (float)u[2]*was[k+2] + (float)u[3]*was[k+3]
           + (float)u[4]*was[k+4] + (float)u[5]*was[k+5]
           + (float)u[6]*was[k+6] + (float)u[7]*was[k+7];
    }
    p[t] = ftanh(acc + bav);
  }
  __syncthreads();
  float m = -1e30f;
  for (int t = tid; t < T_; t += 256) m = fmaxf(m, p[t]);
  for (int off = 32; off; off >>= 1) m = fmaxf(m, __shfl_xor(m, off));
  if ((tid & 63) == 0) red[tid >> 6] = m;
  __syncthreads();
  if (tid == 0) red[8] = fmaxf(fmaxf(red[0], red[1]), fmaxf(red[2], red[3]));
  __syncthreads();
  float smax = red[8];
  float lsum = 0.f;
  for (int t = tid; t < T_; t += 256){
    float e = fexp2(1.44269504f*(p[t] - smax));
    p[t] = e; lsum += e;
  }
  for (int off = 32; off; off >>= 1) lsum += __shfl_xor(lsum, off);
  if ((tid & 63) == 0) red[16 + (tid >> 6)] = lsum;
  __syncthreads();
  float rden = frcp(red[16] + red[17] + red[18] + red[19]);
  int h = tid & (H_ - 1);
  int half = tid >> 7;
  float acc = 0.f;
  for (int t = half*512; t < half*512 + 512; ++t)
    acc += p[t] * (float)out[(size_t)(b*T_ + t)*H_ + h];
  app[tid] = acc;
  __syncthreads();
  if (tid < H_){
    float applied = (app[tid] + app[tid + H_]) * rden;
    float v = applied * Wf[tid];
    for (int off = 32; off; off >>= 1) v += __shfl_xor(v, off);
    if (tid == 0)  red[32] = v;
    if (tid == 64) red[33] = v;
  }
  __syncthreads();
  if (tid == 0) y[b] = fsig(red[32] + red[33] + bfv[0]);
}

// ---------- launch ----------
extern "C" void kernel_launch(void* const* d_in, const int* in_sizes, int n_in,
                              void* d_out, int out_size, void* d_ws, size_t ws_size,
                              hipStream_t stream){
  const float* x   = (const float*)d_in[0];
  const float* Wih = (const float*)d_in[1];
  const float* Whh = (const float*)d_in[2];
  const float* bih = (const float*)d_in[3];
  const float* bhh = (const float*)d_in[4];
  const float* Wa  = (const float*)d_in[5];
  const float* ba  = (const float*)d_in[6];
  const float* Wf  = (const float*)d_in[7];
  const float* bfv = (const float*)d_in[8];
  float* y = (float*)d_out;

  char* ws = (char*)d_ws;
  size_t off = 0;
  auto alloc = [&](size_t bytes) -> void* {
    void* p = ws + off; off += (bytes + 255) & ~(size_t)255; return p;
  };
  _Float16* xcvt  = (_Float16*)alloc((size_t)M_*H_*2);       // 33.5 MB
  _Float16* buf0  = (_Float16*)alloc((size_t)M_*H_*2);       // 33.5 MB
  _Float16* buf1  = (_Float16*)alloc((size_t)M_*H_*2);       // 33.5 MB
  _Float16* Wc    = (_Float16*)alloc((size_t)L_*512*256*2);  // 1.8 MB
  float*    biasp = (float*)   alloc((size_t)L_*512*4);      // 14 KB
  int*      flags = (int*)     alloc((size_t)6*8*128*4);     // 24 KB

  hipMemsetAsync(flags, 0, (size_t)6*8*128*4, stream);
  k_cvt_x<<<2048, 256, 0, stream>>>((const float4*)x, (f16x4*)xcvt, M_*F_/4);
  k_cvt_w<<<3584, 256, 0, stream>>>(Wih, Whh, bih, bhh, Wc, biasp);
  k_recur<<<56, 512, 0, stream>>>(xcvt, buf0, buf1, Wc, (const float4*)biasp, flags);
  k_attn<<<128, 256, 0, stream>>>(buf0, Wa, ba, Wf, bfv, y);
}